// Round 11
// baseline (130.356 us; speedup 1.0000x reference)
//
#include <hip/hip_runtime.h>

#define B 2
#define N 64
#define D 256
#define H 8
#define DK 32
#define M (B * N * N) // 8192

typedef __attribute__((ext_vector_type(8))) short bf16x8;
typedef __attribute__((ext_vector_type(4))) float f32x4;

// P is head-major: 4 proj planes of [b][h][r1*64+r2][32] bf16
#define PROJ_ELEMS (2097152)  // B*H*4096*32

__device__ __forceinline__ ushort f2b(float f) {
    union { float f; unsigned u; } v; v.f = f;
    unsigned r = v.u + 0x7fffu + ((v.u >> 16) & 1u); // RNE
    return (ushort)(r >> 16);
}
__device__ __forceinline__ float b2f(ushort u) {
    union { unsigned u; float f; } v; v.u = ((unsigned)u) << 16; return v.f;
}
// convert 8 bf16 (packed in a float4 register) to 8 floats
__device__ __forceinline__ void cvt8(float4 raw, float* f) {
    const ushort* s = (const ushort*)&raw;
#pragma unroll
    for (int j = 0; j < 8; ++j) f[j] = b2f(s[j]);
}

// async 16B/lane global->LDS (dst = wave-uniform base + lane*16)
__device__ __forceinline__ void glds16(const ushort* g, ushort* l) {
    __builtin_amdgcn_global_load_lds(
        (const __attribute__((address_space(1))) unsigned int*)g,
        (__attribute__((address_space(3))) unsigned int*)l, 16, 0, 0);
}

// ---------------------------------------------------------------------------
// Cast: state f32 -> bf16; 5 weights -> Wcat[1280][256] bf16; biases -> f32.
// ---------------------------------------------------------------------------
__global__ __launch_bounds__(256) void cast_all(const float* __restrict__ state,
                                                const float* __restrict__ W_lk, const float* __restrict__ W_rk,
                                                const float* __restrict__ W_lv, const float* __restrict__ W_rv,
                                                const float* __restrict__ W_o,
                                                const float* __restrict__ b_lk, const float* __restrict__ b_rk,
                                                const float* __restrict__ b_lv, const float* __restrict__ b_rv,
                                                const float* __restrict__ b_o,
                                                ushort* __restrict__ state_bf,
                                                ushort* __restrict__ Wcat,
                                                float* __restrict__ bias_cat) {
    const int gid = blockIdx.x * 256 + threadIdx.x;
    const float* Ws[5] = {W_lk, W_rk, W_lv, W_rv, W_o};
    const float* bs[5] = {b_lk, b_rk, b_lv, b_rv, b_o};

    if (gid < 1280) bias_cat[gid] = bs[gid >> 8][gid & 255];

    if (gid < 524288) {
        float4 v = *(const float4*)&state[(size_t)gid * 4];
        ushort4 o = {f2b(v.x), f2b(v.y), f2b(v.z), f2b(v.w)};
        *(ushort4*)&state_bf[(size_t)gid * 4] = o;
    } else {
        int u = gid - 524288;            // 0..81919
        int row = u >> 6;                // 0..1279
        int k4 = (u & 63) * 4;
        const float* W = Ws[row >> 8];
        float4 v = *(const float4*)&W[(size_t)(row & 255) * 256 + k4];
        ushort4 o = {f2b(v.x), f2b(v.y), f2b(v.z), f2b(v.w)};
        *(ushort4*)&Wcat[(size_t)row * 256 + k4] = o;
    }
}

// ---------------------------------------------------------------------------
// bf16 MFMA GEMM, m97-style. 128x128 tile, 4 waves, 4x4 16x16x32 frags, BK=32.
// RELAYOUT=1 (proj): scatter C into head-major P planes.
// ---------------------------------------------------------------------------
template <int BF16OUT, int RELAYOUT>
__global__ __launch_bounds__(256) void gemm_mfma(const ushort* __restrict__ A,
                                                 const ushort* __restrict__ Bw,
                                                 const float* __restrict__ bias,
                                                 void* __restrict__ Cv, int ldc) {
    __shared__ __align__(16) ushort As[128 * 32];
    __shared__ __align__(16) ushort Bs[128 * 32];
    const int tid = threadIdx.x;
    const int lane = tid & 63;
    const int wave = tid >> 6;
    const int wm = (wave & 1) * 64;
    const int wn = (wave >> 1) * 64;
    const int row0 = blockIdx.x * 128;
    const int col0 = blockIdx.y * 128;

    const int lr = lane >> 2;        // 0..15
    const int lkq = (lane & 3) * 8;  // {0,8,16,24}

    const ushort* gA0 = A + (size_t)(row0 + wave * 32 + lr) * 256 + lkq;
    const ushort* gA1 = gA0 + 16 * 256;
    const ushort* gB0 = Bw + (size_t)(col0 + wave * 32 + lr) * 256 + lkq;
    const ushort* gB1 = gB0 + 16 * 256;
    ushort* lA0 = &As[(wave * 32) * 32];
    ushort* lA1 = &As[(wave * 32 + 16) * 32];
    ushort* lB0 = &Bs[(wave * 32) * 32];
    ushort* lB1 = &Bs[(wave * 32 + 16) * 32];

    const int fr = lane & 15;
    const int fk = (lane >> 4) * 8;

    f32x4 acc[4][4] = {};

    for (int k0 = 0; k0 < 256; k0 += 32) {
        __syncthreads();
        glds16(gA0 + k0, lA0);
        glds16(gA1 + k0, lA1);
        glds16(gB0 + k0, lB0);
        glds16(gB1 + k0, lB1);
        __syncthreads();

        bf16x8 af[4], bf[4];
#pragma unroll
        for (int i = 0; i < 4; ++i)
            af[i] = *(const bf16x8*)&As[(wm + i * 16 + fr) * 32 + fk];
#pragma unroll
        for (int j = 0; j < 4; ++j)
            bf[j] = *(const bf16x8*)&Bs[(wn + j * 16 + fr) * 32 + fk];
#pragma unroll
        for (int i = 0; i < 4; ++i)
#pragma unroll
            for (int j = 0; j < 4; ++j)
                acc[i][j] = __builtin_amdgcn_mfma_f32_16x16x32_bf16(af[i], bf[j], acc[i][j], 0, 0, 0);
    }

#pragma unroll
    for (int j = 0; j < 4; ++j) {
        const int col = col0 + wn + j * 16 + (lane & 15);
        const float bv = bias[col];
#pragma unroll
        for (int i = 0; i < 4; ++i) {
            const int rbase = row0 + wm + i * 16 + (lane >> 4) * 4;
#pragma unroll
            for (int r = 0; r < 4; ++r) {
                float o = acc[i][j][r] + bv;
                if (RELAYOUT) {
                    const int row = rbase + r;
                    const int bb = row >> 12, rr = row & 4095;
                    const int proj = col >> 8, hh = (col >> 5) & 7, dk = col & 31;
                    ((ushort*)Cv)[(size_t)proj * PROJ_ELEMS +
                                  ((size_t)(bb * 8 + hh) * 4096 + rr) * 32 + dk] = f2b(o);
                } else if (BF16OUT) {
                    ((ushort*)Cv)[(size_t)(rbase + r) * ldc + col] = f2b(o);
                } else {
                    ((float*)Cv)[(size_t)(rbase + r) * ldc + col] = o;
                }
            }
        }
    }
}

// ---------------------------------------------------------------------------
// FUSED scores + online-softmax + gated combine, v6.
// Tile = 16x x 8y per (b,h); grid (4,8,16) = 512 blocks, 256 threads (4 waves).
// a-chunk = 8, LDS ~41 KB -> up to 3 blocks/CU, avg 2 resident: independent
// blocks hide each other's barrier stalls. No launch_bounds min-waves (R9
// lesson: forcing it spills; 2 waves/EU needs only <=256 VGPR).
// LK/RK: per-lane 16B global loads ARE the MFMA frags (head-major P).
// Scores MFMA computes 16y, keeps y<8 (waste is free at MfmaUtil ~0.2%).
// LDS layouts (audited <=2-way reads, <=4-way staging stores):
//   LVs f32 [x*8+a][44]  (global reads contiguous over a; gate 2-way)
//   RVs f32 [a*8+y][44]  (global reads contiguous over y)
//   atts f32 [a*16+x][12]
// Gate thread = (xg:2x, yg:2y, dg:4d): per a 4xb128 + 2xb64 LDS, 32 VALU.
// ---------------------------------------------------------------------------
__global__ __launch_bounds__(256) void fused_attn(const ushort* __restrict__ P,
                                                  const unsigned char* __restrict__ mask,
                                                  ushort* __restrict__ xbuf) {
    __shared__ __align__(16) float LVs[128 * 44];
    __shared__ __align__(16) float RVs[64 * 44];
    __shared__ __align__(16) float atts[128 * 12];
    __shared__ float mstate[16 * 10];
    __shared__ float lstate[16 * 10];
    __shared__ float alphas[16 * 10];

    const int bh = blockIdx.z;
    const int b = bh >> 3, h = bh & 7;
    const int x0 = blockIdx.x * 16, y0 = blockIdx.y * 8;
    const int tid = threadIdx.x;
    const int lane = tid & 63, wave = tid >> 6;

    const size_t HB = (size_t)bh * 4096 * 32;   // head slice offset (elements)
    const ushort* PLK = P + HB;
    const ushort* PRK = P + (size_t)1 * PROJ_ELEMS + HB;
    const ushort* PLV = P + (size_t)2 * PROJ_ELEMS + HB;
    const ushort* PRV = P + (size_t)3 * PROJ_ELEMS + HB;

    // gate coords: x = xg*2+i, y = yg*2+j, d = dg*4..dg*4+3
    const int dg = tid & 7, yg = (tid >> 3) & 3, xg = tid >> 5;
    // softmax coords (threads 0..127)
    const int sx = tid >> 3, sy = tid & 7;
    if (tid < 128) {
        mstate[sx * 10 + sy] = -3.0e38f;
        lstate[sx * 10 + sy] = 0.0f;
    }

    f32x4 acc[2][2] = {};
    const float scale = 0.17677669529663687f; // 1/sqrt(32)

    for (int ac = 0; ac < N; ac += 8) {
        __syncthreads();
        // ---- stage LV/RV (f32) + scores (direct-global MFMA frags) ----
        {
            // LV rows (x = r>>3, a = r&7): 128 rows x 32 f; thread does 16 (q half)
            const int r = tid >> 1, q = tid & 1;
            const int xL = r >> 3, aL = r & 7;
            float f[16];
            cvt8(*(const float4*)&PLV[((size_t)(x0 + xL) * 64 + ac + aL) * 32 + q * 16], f);
            cvt8(*(const float4*)&PLV[((size_t)(x0 + xL) * 64 + ac + aL) * 32 + q * 16 + 8], f + 8);
            *(float4*)&LVs[r * 44 + q * 16]      = make_float4(f[0], f[1], f[2], f[3]);
            *(float4*)&LVs[r * 44 + q * 16 + 4]  = make_float4(f[4], f[5], f[6], f[7]);
            *(float4*)&LVs[r * 44 + q * 16 + 8]  = make_float4(f[8], f[9], f[10], f[11]);
            *(float4*)&LVs[r * 44 + q * 16 + 12] = make_float4(f[12], f[13], f[14], f[15]);

            // RV rows (a = r2>>3, y = r2&7): 64 rows x 32 f; thread does 8 (q2 quarter)
            const int r2 = tid >> 2, q2 = tid & 3;
            const int aR = r2 >> 3, yR = r2 & 7;
            cvt8(*(const float4*)&PRV[((size_t)(ac + aR) * 64 + y0 + yR) * 32 + q2 * 8], f);
            *(float4*)&RVs[r2 * 44 + q2 * 8]     = make_float4(f[0], f[1], f[2], f[3]);
            *(float4*)&RVs[r2 * 44 + q2 * 8 + 4] = make_float4(f[4], f[5], f[6], f[7]);

            // scores: wave w -> a = 2w, 2w+1; keep y<8
            const int fr = lane & 15, fk = (lane >> 4) * 8;
            const int yq = lane & 15, xq = (lane >> 4) * 4;
#pragma unroll
            for (int aw = 0; aw < 2; ++aw) {
                const int a = wave * 2 + aw;
                bf16x8 af = *(const bf16x8*)&PLK[((size_t)(x0 + fr) * 64 + ac + a) * 32 + fk];
                bf16x8 bf = *(const bf16x8*)&PRK[((size_t)(ac + a) * 64 + y0 + fr) * 32 + fk];
                f32x4 s = {};
                s = __builtin_amdgcn_mfma_f32_16x16x32_bf16(af, bf, s, 0, 0, 0);
                if (yq < 8) {
#pragma unroll
                    for (int rr = 0; rr < 4; ++rr) {
                        const int x = xq + rr;
                        float sv = s[rr] * scale;
                        if (mask[((size_t)(b * N + x0 + x) * N + ac + a) * N + y0 + yq]) sv = -1000.0f;
                        atts[(a * 16 + x) * 12 + yq] = sv;
                    }
                }
            }
        }
        __syncthreads();

        // ---- online softmax over 8-a chunk: threads 0..127 own (sx, sy) ----
        if (tid < 128) {
            float s8[8];
            float mc = -3.0e38f;
#pragma unroll
            for (int a = 0; a < 8; ++a) {
                s8[a] = atts[(a * 16 + sx) * 12 + sy];
                mc = fmaxf(mc, s8[a]);
            }
            const float mold = mstate[sx * 10 + sy];
            const float mnew = fmaxf(mold, mc);
            const float alpha = __expf(mold - mnew);
            float ps = 0.0f;
#pragma unroll
            for (int a = 0; a < 8; ++a) {
                float p = __expf(s8[a] - mnew);
                atts[(a * 16 + sx) * 12 + sy] = p;
                ps += p;
            }
            lstate[sx * 10 + sy] = lstate[sx * 10 + sy] * alpha + ps;
            mstate[sx * 10 + sy] = mnew;
            alphas[sx * 10 + sy] = alpha;
        }
        __syncthreads();

        // ---- rescale + gate: thread (xg:2x, yg:2y, dg:4d) ----
#pragma unroll
        for (int i = 0; i < 2; ++i) {
            float2 av = *(const float2*)&alphas[(xg * 2 + i) * 10 + yg * 2];
            acc[i][0] *= av.x;
            acc[i][1] *= av.y;
        }
#pragma unroll
        for (int a = 0; a < 8; ++a) {
            f32x4 lv[2], rv[2];
#pragma unroll
            for (int i = 0; i < 2; ++i)
                lv[i] = *(const f32x4*)&LVs[((xg * 2 + i) * 8 + a) * 44 + dg * 4];
#pragma unroll
            for (int j = 0; j < 2; ++j)
                rv[j] = *(const f32x4*)&RVs[(a * 8 + yg * 2 + j) * 44 + dg * 4];
#pragma unroll
            for (int i = 0; i < 2; ++i) {
                float2 at = *(const float2*)&atts[(a * 16 + xg * 2 + i) * 12 + yg * 2];
                acc[i][0] += (at.x * lv[i]) * rv[0];
                acc[i][1] += (at.y * lv[i]) * rv[1];
            }
        }
    }

    // ---- epilogue: divide by l, store bf16 (8 lanes x 8B contiguous) ----
#pragma unroll
    for (int i = 0; i < 2; ++i) {
        const int x = xg * 2 + i;
        float2 lq = *(const float2*)&lstate[x * 10 + yg * 2];
        const float* lp = (const float*)&lq;
#pragma unroll
        for (int j = 0; j < 2; ++j) {
            const float il = 1.0f / lp[j];
            f32x4 o = acc[i][j] * il;
            ushort4 ob = {f2b(o[0]), f2b(o[1]), f2b(o[2]), f2b(o[3])};
            *(ushort4*)&xbuf[(((size_t)b * N + x0 + x) * N + y0 + yg * 2 + j) * D + h * DK + dg * 4] = ob;
        }
    }
}

// ---------------------------------------------------------------------------
extern "C" void kernel_launch(void* const* d_in, const int* in_sizes, int n_in,
                              void* d_out, int out_size, void* d_ws, size_t ws_size,
                              hipStream_t stream) {
    const float* state = (const float*)d_in[0];
    const unsigned char* mask = (const unsigned char*)d_in[1];
    const float* W_lk = (const float*)d_in[2];
    const float* b_lk = (const float*)d_in[3];
    const float* W_rk = (const float*)d_in[4];
    const float* b_rk = (const float*)d_in[5];
    const float* W_lv = (const float*)d_in[6];
    const float* b_lv = (const float*)d_in[7];
    const float* W_rv = (const float*)d_in[8];
    const float* b_rv = (const float*)d_in[9];
    const float* W_o = (const float*)d_in[10];
    const float* b_o = (const float*)d_in[11];
    float* out = (float*)d_out;

    char* ws = (char*)d_ws;
    ushort* P_bf = (ushort*)ws;                          // 4 proj planes, 16.8 MB
    ws += (size_t)4 * PROJ_ELEMS * 2;
    float* bias_cat = (float*)ws;                        // 1280 f32
    ws += 1280 * 4;
    ushort* state_bf = (ushort*)ws;                      // 4 MB
    ws += (size_t)M * D * 2;
    ushort* Wcat = (ushort*)ws;                          // 0.65 MB
    ws += (size_t)1280 * 256 * 2;
    ushort* xbuf_bf = (ushort*)ws;                       // 4 MB

    cast_all<<<2368, 256, 0, stream>>>(state, W_lk, W_rk, W_lv, W_rv, W_o,
                                       b_lk, b_rk, b_lv, b_rv, b_o,
                                       state_bf, Wcat, bias_cat);
    gemm_mfma<1, 1><<<dim3(M / 128, 8), 256, 0, stream>>>(state_bf, Wcat, bias_cat, P_bf, 1024);
    fused_attn<<<dim3(4, 8, B * H), 256, 0, stream>>>(P_bf, mask, xbuf_bf);
    gemm_mfma<0, 0><<<dim3(M / 128, 2), 256, 0, stream>>>(xbuf_bf, Wcat + 1024 * 256, bias_cat + 1024, out, 256);
}